// Round 13
// baseline (210.664 us; speedup 1.0000x reference)
//
#include <hip/hip_runtime.h>
#include <math.h>

#define BB 2
#define LL 2048
#define DD 512
#define HH 8
#define DK 64
#define SK 40   // sample_k
#define UU 40   // top-k u
#define BH (BB*HH)   // 16

typedef __attribute__((ext_vector_type(8))) __bf16 bf16x8;
typedef __attribute__((ext_vector_type(4))) float f32x4;

__device__ inline ushort f2bf_rn(float f) {
    unsigned u = __float_as_uint(f);
    unsigned r = (u + 0x7fffu + ((u >> 16) & 1u)) >> 16;
    return (ushort)r;
}
__device__ inline float bf2f(ushort h) { return __uint_as_float(((unsigned)h) << 16); }

__device__ __forceinline__ void gload16(const ushort* g, void* l) {
    __builtin_amdgcn_global_load_lds(
        (const __attribute__((address_space(1))) unsigned int*)g,
        (__attribute__((address_space(3))) unsigned int*)l,
        16, 0, 0);
}

__device__ __forceinline__ void fill_unit(float* __restrict__ attns, int fu, int tid) {
    const float c = 1.0f / (float)LL;
    const float4 val = make_float4(c, c, c, c);
    float4* p = (float4*)attns + (long)fu * 8192 + tid;
    #pragma unroll
    for (int i = 0; i < 32; ++i) p[i * 256] = val;
}

// =============== K0: pack (blocks 0..1407) || fill units 0..639 (1408..2047) ===============
__global__ __launch_bounds__(256) void k0_pack_fill(
    const float* __restrict__ x,
    const float* __restrict__ Wq, const float* __restrict__ Wk, const float* __restrict__ Wv,
    ushort* __restrict__ Ah, ushort* __restrict__ Al,
    ushort* __restrict__ Bh, ushort* __restrict__ Bl,
    float* __restrict__ attns)
{
    const int bid = blockIdx.x;
    if (bid >= 1408) {
        fill_unit(attns, bid - 1408, threadIdx.x);
        return;
    }
    const float* src; ushort* dh; ushort* dl; int p = -1;
    if (bid < 1024) {
        const int g = bid * 256 + threadIdx.x;
        const int r = g >> 6, c = (g & 63) * 8;
        src = x + (long)r * DD + c;
        dh = Ah + (long)r * DD + c;
        dl = Al + (long)r * DD + c;
    } else {
        const int wb = bid - 1024;
        p = wb >> 7;
        const float* W = (p == 0) ? Wq : ((p == 1) ? Wk : Wv);
        const int rem = (wb & 127) * 256 + threadIdx.x;
        const int r = rem >> 6, c = (rem & 63) * 8;
        src = W + (long)r * DD + c;
        dh = Bh + ((long)p * DD + r) * DD + c;
        dl = Bl + ((long)p * DD + r) * DD + c;
    }
    const float4 f0 = *(const float4*)&src[0];
    const float4 f1 = *(const float4*)&src[4];
    float f[8] = {f0.x, f0.y, f0.z, f0.w, f1.x, f1.y, f1.z, f1.w};
    union { ushort s[8]; uint4 u; } H, L;
    #pragma unroll
    for (int i = 0; i < 8; ++i) {
        H.s[i] = f2bf_rn(f[i]);
        L.s[i] = f2bf_rn(f[i] - bf2f(H.s[i]));
    }
    *(uint4*)dh = H.u;
    if (p != 2) *(uint4*)dl = L.u;   // Wv needs no lo-part (v is 1-term bf16)
}

// =============== K1: MFMA proj (blocks 0..383; v=1-term) || fill units 640..1343 (384..1087) ===============
__global__ __launch_bounds__(256) void k1_proj_fill(
    const ushort* __restrict__ Ah, const ushort* __restrict__ Al,
    const ushort* __restrict__ Bh, const ushort* __restrict__ Bl,
    const float* __restrict__ bq, const float* __restrict__ bk_, const float* __restrict__ bv,
    float* __restrict__ q, float* __restrict__ k, float* __restrict__ v,
    float* __restrict__ attns)
{
    const int tid = threadIdx.x;

    if (blockIdx.x >= 384) {
        fill_unit(attns, 640 + (blockIdx.x - 384), tid);
        return;
    }

    const int pz = blockIdx.x >> 7;
    const int rem = blockIdx.x & 127;
    const int o0 = (rem >> 5) * 128;
    const int m0 = (rem & 31) * 128;
    const float* bias = (pz == 0) ? bq : ((pz == 1) ? bk_ : bv);
    float* out = (pz == 0) ? q : ((pz == 1) ? k : v);

    const ushort* Bp = Bh + (long)pz * DD * DD;
    const ushort* Blp = Bl + (long)pz * DD * DD;
    const ushort* segA[3] = {Ah, Ah, Al};
    const ushort* segB[3] = {Bp, Blp, Bp};

    __shared__ __attribute__((aligned(16))) ushort As[128 * 64];
    __shared__ __attribute__((aligned(16))) ushort Bs[128 * 64];

    const int lane = tid & 63, w = tid >> 6;
    const int wr = w >> 1, wc = w & 1;
    const int ln15 = lane & 15;
    const int l3 = lane >> 3, l7 = (lane & 7) * 8;

    f32x4 acc[4][4] = {};

    // v (pz==2): single bf16 term xh*Wvh (8 steps); q,k: full 3-term split (24 steps)
    const int tmax = (pz == 2) ? 8 : 24;
    for (int t = 0; t < tmax; ++t) {
        const ushort* Aseg = segA[t >> 3];
        const ushort* Bseg = segB[t >> 3];
        const int k0 = (t & 7) * 64;
        __syncthreads();
        #pragma unroll
        for (int c = 0; c < 8; ++c) {
            const int j = w * 8 + c;
            if (j < 16) {
                gload16(Aseg + (long)(m0 + j * 8 + l3) * DD + k0 + l7,
                        (char*)As + j * 1024);
            } else {
                const int j2 = j - 16;
                gload16(Bseg + (long)(o0 + j2 * 8 + l3) * DD + k0 + l7,
                        (char*)Bs + j2 * 1024);
            }
        }
        __syncthreads();
        #pragma unroll
        for (int ks = 0; ks < 2; ++ks) {
            const int kb = ks * 64 + (lane >> 4) * 16;
            bf16x8 bfr[4];
            #pragma unroll
            for (int jj = 0; jj < 4; ++jj)
                bfr[jj] = *(const bf16x8*)((const char*)Bs + (wc * 64 + jj * 16 + ln15) * 128 + kb);
            #pragma unroll
            for (int i = 0; i < 4; ++i) {
                bf16x8 af = *(const bf16x8*)((const char*)As + (wr * 64 + i * 16 + ln15) * 128 + kb);
                #pragma unroll
                for (int jj = 0; jj < 4; ++jj)
                    acc[i][jj] = __builtin_amdgcn_mfma_f32_16x16x32_bf16(af, bfr[jj], acc[i][jj], 0, 0, 0);
            }
        }
    }

    const int n_base = o0 + wc * 64;
    float bb[4];
    #pragma unroll
    for (int jj = 0; jj < 4; ++jj) bb[jj] = bias[n_base + jj * 16 + ln15];
    #pragma unroll
    for (int i = 0; i < 4; ++i) {
        #pragma unroll
        for (int jj = 0; jj < 4; ++jj) {
            const int n = n_base + jj * 16 + ln15;
            #pragma unroll
            for (int r = 0; r < 4; ++r) {
                const int m = m0 + wr * 64 + i * 16 + (lane >> 4) * 4 + r;
                out[(((long)(m >> 11) * HH + (n >> 6)) * LL + (m & (LL - 1))) * DK + (n & 63)] =
                    acc[i][jj][r] + bb[jj];
            }
        }
    }
}

// =============== K2: qk 4-way XCD-swizzled (0..511) || cumsum_p1 (512..767) || fill units 1344..2047 (768..1471) ===============
__global__ __launch_bounds__(256) void k2_qk_cumsum1(
    const float* __restrict__ q, const float* __restrict__ k, const float* __restrict__ v,
    const int* __restrict__ idxs, float* __restrict__ M, float* __restrict__ sums,
    float* __restrict__ attns)
{
    const int tid = threadIdx.x;

    if (blockIdx.x >= 768) {
        fill_unit(attns, 1344 + (blockIdx.x - 768), tid);
        return;
    }

    if (blockIdx.x >= 512) {
        const int b = blockIdx.x - 512;          // 0..255, 16 per bh
        const int r8 = b & 7, t = b >> 3;        // t: 0..31
        const int bh = ((t >> 4) << 3) | r8;     // bh % 8 == bid % 8
        const int cgrp = t & 15;
        const int d = tid & 63, sc_ = tid >> 6;
        const int chunk = cgrp * 4 + sc_;
        const float* vb = v + ((long)bh * LL + chunk * 32) * DK + d;
        float s = 0.f;
        #pragma unroll
        for (int r = 0; r < 32; ++r) s += vb[r * DK];
        sums[((long)bh * 64 + chunk) * DK + d] = s;
        return;
    }

    // qk: 32 blocks per bh, swizzled so all land on XCD (bh & 7)
    const int r8 = blockIdx.x & 7, t = blockIdx.x >> 3;   // t: 0..63
    const int bh = ((t >> 5) << 3) | r8;
    const int j = t & 31;                                 // query chunk within bh
    const int l = j * 64 + (tid >> 2);
    const int part = tid & 3;
    const float* qr = q + ((long)bh * LL + l) * DK;
    float4 qv[16];
    #pragma unroll
    for (int i = 0; i < 16; ++i) qv[i] = *(const float4*)&qr[i * 4];

    const int* ir = idxs + (long)l * SK + part * 10;
    const float* kb = k + (long)bh * LL * DK;
    float mx = -INFINITY, sm = 0.f;
    #pragma unroll
    for (int s = 0; s < 10; ++s) {
        const float* kr = kb + (long)ir[s] * DK;
        float acc = 0.f;
        #pragma unroll
        for (int i = 0; i < 16; ++i) {
            float4 kv = *(const float4*)&kr[i * 4];
            acc += qv[i].x * kv.x + qv[i].y * kv.y + qv[i].z * kv.z + qv[i].w * kv.w;
        }
        mx = fmaxf(mx, acc); sm += acc;
    }
    mx = fmaxf(mx, __shfl_xor(mx, 1, 64));
    mx = fmaxf(mx, __shfl_xor(mx, 2, 64));
    sm += __shfl_xor(sm, 1, 64);
    sm += __shfl_xor(sm, 2, 64);
    if (part == 0) M[(long)bh * LL + l] = mx - sm * (1.0f / (float)LL);
}

// =============== K4: topk-recompute + {scores 5 rows (0..127) | cum-emit (128..383)}, XCD-swizzled — R12 verbatim ===============
__global__ __launch_bounds__(256) void k4_all(
    const float* __restrict__ q, const float* __restrict__ k, const float* __restrict__ v,
    const float* __restrict__ M, const float* __restrict__ sums,
    float* __restrict__ attns, float* __restrict__ ctx)
{
    const int tid = threadIdx.x;
    const bool isCum = blockIdx.x >= 128;
    int bh, role;
    if (isCum) {
        const int b = blockIdx.x - 128;
        const int r8 = b & 7, t = b >> 3;
        bh = ((t >> 4) << 3) | r8;
        role = t & 15;
    } else {
        const int r8 = blockIdx.x & 7, t = blockIdx.x >> 3;
        bh = ((t >> 3) << 3) | r8;
        role = t & 7;
    }

    __shared__ int list[UU];
    __shared__ unsigned bmap[64];

    if (tid < 64) bmap[tid] = 0u;
    __syncthreads();
    if (tid < 64) {
        const int lane = tid;
        float vals[32];
        #pragma unroll
        for (int r = 0; r < 32; ++r) vals[r] = M[(long)bh * LL + r * 64 + lane];
        for (int it = 0; it < UU; ++it) {
            float lm = vals[0];
            #pragma unroll
            for (int r = 1; r < 32; ++r) lm = fmaxf(lm, vals[r]);
            float wm = lm;
            #pragma unroll
            for (int s = 1; s < 64; s <<= 1) wm = fmaxf(wm, __shfl_xor(wm, s, 64));
            unsigned long long mask = __ballot(lm == wm);
            int first = (int)__ffsll(mask) - 1;
            if (lane == first) {
                #pragma unroll
                for (int r = 0; r < 32; ++r) {
                    if (vals[r] == wm) { list[it] = r * 64 + lane; vals[r] = -INFINITY; break; }
                }
            }
        }
    }
    __syncthreads();
    if (tid < UU) atomicOr(&bmap[list[tid] >> 5], 1u << (list[tid] & 31));
    __syncthreads();

    if (isCum) {
        const int d = tid & 63, sc_ = tid >> 6;
        const int chunk = role * 4 + sc_;
        float carry = 0.f;
        for (int c = 0; c < chunk; ++c) carry += sums[((long)bh * 64 + c) * DK + d];
        const float* vb = v + ((long)bh * LL + chunk * 32) * DK + d;
        float* cb = ctx + ((long)bh * LL + chunk * 32) * DK + d;
        float run = carry;
        #pragma unroll
        for (int r = 0; r < 32; ++r) {
            run += vb[r * DK];
            const int l = chunk * 32 + r;
            if (!((bmap[l >> 5] >> (l & 31)) & 1u)) cb[r * DK] = run;
        }
        return;
    }

    const int g = role;
    const int lane = tid & 63, wave = tid >> 6;
    __shared__ float qs[5][DK];
    __shared__ float sc[5][LL];          // 40 KB
    __shared__ float red[5][4];
    __shared__ float red2[4][5][DK];     // 5 KB

    if (tid < 80) {
        int u = tid >> 4, c4 = (tid & 15) * 4;
        *(float4*)&qs[u][c4] = *(const float4*)&q[((long)bh * LL + list[g * 5 + u]) * DK + c4];
    }
    __syncthreads();

    const float* kb = k + (long)bh * LL * DK;
    float a[8][5] = {};
    #pragma unroll
    for (int c = 0; c < DK; c += 4) {
        float4 qv[5];
        #pragma unroll
        for (int u = 0; u < 5; ++u) qv[u] = *(const float4*)&qs[u][c];
        #pragma unroll
        for (int r = 0; r < 8; ++r) {
            float4 kv = *(const float4*)&kb[(long)(tid + r * 256) * DK + c];
            #pragma unroll
            for (int u = 0; u < 5; ++u)
                a[r][u] += qv[u].x * kv.x + qv[u].y * kv.y + qv[u].z * kv.z + qv[u].w * kv.w;
        }
    }
    const float scale = 0.125f;
    #pragma unroll
    for (int r = 0; r < 8; ++r)
        #pragma unroll
        for (int u = 0; u < 5; ++u)
            sc[u][tid + r * 256] = a[r][u] * scale;
    __syncthreads();

    float xv[5][8];
    #pragma unroll
    for (int u = 0; u < 5; ++u) {
        float4 t0 = *(const float4*)&sc[u][tid * 8];
        float4 t1 = *(const float4*)&sc[u][tid * 8 + 4];
        xv[u][0] = t0.x; xv[u][1] = t0.y; xv[u][2] = t0.z; xv[u][3] = t0.w;
        xv[u][4] = t1.x; xv[u][5] = t1.y; xv[u][6] = t1.z; xv[u][7] = t1.w;
    }
    float mloc[5];
    #pragma unroll
    for (int u = 0; u < 5; ++u) {
        float m = xv[u][0];
        #pragma unroll
        for (int i = 1; i < 8; ++i) m = fmaxf(m, xv[u][i]);
        #pragma unroll
        for (int s = 1; s < 64; s <<= 1) m = fmaxf(m, __shfl_xor(m, s, 64));
        if (lane == 0) red[u][wave] = m;
        mloc[u] = m;
    }
    __syncthreads();
    #pragma unroll
    for (int u = 0; u < 5; ++u)
        mloc[u] = fmaxf(fmaxf(red[u][0], red[u][1]), fmaxf(red[u][2], red[u][3]));
    __syncthreads();
    #pragma unroll
    for (int u = 0; u < 5; ++u) {
        float s = 0.f;
        #pragma unroll
        for (int i = 0; i < 8; ++i) { xv[u][i] = expf(xv[u][i] - mloc[u]); s += xv[u][i]; }
        #pragma unroll
        for (int st = 1; st < 64; st <<= 1) s += __shfl_xor(s, st, 64);
        if (lane == 0) red[u][wave] = s;
    }
    __syncthreads();
    #pragma unroll
    for (int u = 0; u < 5; ++u) {
        float inv = 1.0f / (red[u][0] + red[u][1] + red[u][2] + red[u][3]);
        float* row = attns + ((long)bh * LL + list[g * 5 + u]) * LL;
        float4 o0, o1;
        o0.x = xv[u][0] * inv; o0.y = xv[u][1] * inv; o0.z = xv[u][2] * inv; o0.w = xv[u][3] * inv;
        o1.x = xv[u][4] * inv; o1.y = xv[u][5] * inv; o1.z = xv[u][6] * inv; o1.w = xv[u][7] * inv;
        *(float4*)&row[tid * 8] = o0;
        *(float4*)&row[tid * 8 + 4] = o1;
        *(float4*)&sc[u][tid * 8] = o0;
        *(float4*)&sc[u][tid * 8 + 4] = o1;
    }
    __syncthreads();

    const int d = tid & 63, part = tid >> 6;
    const float* vb = v + (long)bh * LL * DK + d;
    float ua[5] = {};
    for (int l0 = part * 512; l0 < part * 512 + 512; l0 += 4) {
        float vv0 = vb[(long)(l0 + 0) * DK];
        float vv1 = vb[(long)(l0 + 1) * DK];
        float vv2 = vb[(long)(l0 + 2) * DK];
        float vv3 = vb[(long)(l0 + 3) * DK];
        #pragma unroll
        for (int u = 0; u < 5; ++u) {
            float4 pv = *(const float4*)&sc[u][l0];
            ua[u] += pv.x * vv0 + pv.y * vv1 + pv.z * vv2 + pv.w * vv3;
        }
    }
    #pragma unroll
    for (int u = 0; u < 5; ++u) red2[part][u][d] = ua[u];
    __syncthreads();
    if (part == 0) {
        #pragma unroll
        for (int u = 0; u < 5; ++u) {
            float s = red2[0][u][d] + red2[1][u][d] + red2[2][u][d] + red2[3][u][d];
            ctx[((long)bh * LL + list[g * 5 + u]) * DK + d] = s;
        }
    }
}

extern "C" void kernel_launch(void* const* d_in, const int* in_sizes, int n_in,
                              void* d_out, int out_size, void* d_ws, size_t ws_size,
                              hipStream_t stream) {
    const float* x  = (const float*)d_in[0];
    const float* Wq = (const float*)d_in[1];
    const float* bq = (const float*)d_in[2];
    const float* Wk = (const float*)d_in[3];
    const float* bk = (const float*)d_in[4];
    const float* Wv = (const float*)d_in[5];
    const float* bv = (const float*)d_in[6];
    const int* idxs = (const int*)d_in[7];

    float* ctx   = (float*)d_out;                            // B*H*L*DK (8 MB)
    float* attns = (float*)d_out + (long)BB * HH * LL * DK;  // B*H*L*L (268 MB)

    char* w = (char*)d_ws;
    float* q    = (float*)w; w += (size_t)BB * HH * LL * DK * 4;
    float* k    = (float*)w; w += (size_t)BB * HH * LL * DK * 4;
    float* v    = (float*)w; w += (size_t)BB * HH * LL * DK * 4;
    float* M    = (float*)w; w += (size_t)BB * HH * LL * 4;
    float* sums = (float*)w; w += (size_t)BH * 64 * DK * 4;
    ushort* Bh  = (ushort*)w; w += (size_t)3 * DD * DD * 2;
    ushort* Bl  = (ushort*)w; w += (size_t)3 * DD * DD * 2;

    // Ah/Al live in the ctx output region (consumed by K1; ctx written in K4)
    ushort* Ah = (ushort*)ctx;                  // 4 MB
    ushort* Al = Ah + (size_t)4096 * DD;        // 4 MB

    // K0: split-bf16 packing (1408) || fill units 0..639
    k0_pack_fill<<<1408 + 640, 256, 0, stream>>>(x, Wq, Wk, Wv, Ah, Al, Bh, Bl, attns);

    // K1: MFMA projections, v 1-term (384) || fill units 640..1343
    k1_proj_fill<<<384 + 704, 256, 0, stream>>>(Ah, Al, Bh, Bl, bq, bk, bv, q, k, v, attns);

    // K2: sampled QK^T 4-way XCD-swizzled (512) || cumsum sums (256) || fill units 1344..2047
    k2_qk_cumsum1<<<512 + 256 + 704, 256, 0, stream>>>(q, k, v, idxs, M, sums, attns);

    // K4: topk-recompute + scores/softmax/upd/scatter (128) || cumsum emit (256), XCD-swizzled
    k4_all<<<128 + 256, 256, 0, stream>>>(q, k, v, M, sums, attns, ctx);
}

// Round 14
// 198.445 us; speedup vs baseline: 1.0616x; 1.0616x over previous
//
#include <hip/hip_runtime.h>
#include <math.h>

#define BB 2
#define LL 2048
#define DD 512
#define HH 8
#define DK 64
#define SK 40   // sample_k
#define UU 40   // top-k u
#define BH (BB*HH)   // 16

typedef __attribute__((ext_vector_type(8))) __bf16 bf16x8;
typedef __attribute__((ext_vector_type(4))) float f32x4;

__device__ inline ushort f2bf_rn(float f) {
    unsigned u = __float_as_uint(f);
    unsigned r = (u + 0x7fffu + ((u >> 16) & 1u)) >> 16;
    return (ushort)r;
}
__device__ inline float bf2f(ushort h) { return __uint_as_float(((unsigned)h) << 16); }

__device__ __forceinline__ void gload16(const ushort* g, void* l) {
    __builtin_amdgcn_global_load_lds(
        (const __attribute__((address_space(1))) unsigned int*)g,
        (__attribute__((address_space(3))) unsigned int*)l,
        16, 0, 0);
}

// =============== K0: pack x -> Ah/Al, W -> Bh/Bl (split-bf16); Wv lo skipped ===============
__global__ __launch_bounds__(256) void pack_split(
    const float* __restrict__ x,
    const float* __restrict__ Wq, const float* __restrict__ Wk, const float* __restrict__ Wv,
    ushort* __restrict__ Ah, ushort* __restrict__ Al,
    ushort* __restrict__ Bh, ushort* __restrict__ Bl)
{
    const int bid = blockIdx.x;
    const float* src; ushort* dh; ushort* dl; int p = -1;
    if (bid < 1024) {
        const int g = bid * 256 + threadIdx.x;
        const int r = g >> 6, c = (g & 63) * 8;
        src = x + (long)r * DD + c;
        dh = Ah + (long)r * DD + c;
        dl = Al + (long)r * DD + c;
    } else {
        const int wb = bid - 1024;
        p = wb >> 7;
        const float* W = (p == 0) ? Wq : ((p == 1) ? Wk : Wv);
        const int rem = (wb & 127) * 256 + threadIdx.x;
        const int r = rem >> 6, c = (rem & 63) * 8;
        src = W + (long)r * DD + c;
        dh = Bh + ((long)p * DD + r) * DD + c;
        dl = Bl + ((long)p * DD + r) * DD + c;
    }
    const float4 f0 = *(const float4*)&src[0];
    const float4 f1 = *(const float4*)&src[4];
    float f[8] = {f0.x, f0.y, f0.z, f0.w, f1.x, f1.y, f1.z, f1.w};
    union { ushort s[8]; uint4 u; } H, L;
    #pragma unroll
    for (int i = 0; i < 8; ++i) {
        H.s[i] = f2bf_rn(f[i]);
        L.s[i] = f2bf_rn(f[i] - bf2f(H.s[i]));
    }
    *(uint4*)dh = H.u;
    if (p != 2) *(uint4*)dl = L.u;   // Wv lo never read (v is 1-term bf16)
}

// =============== K1: MFMA proj (0..383; v=1-term) || fill attns ALL units (384..2431) ===============
__global__ __launch_bounds__(256) void k1_proj_fill(
    const ushort* __restrict__ Ah, const ushort* __restrict__ Al,
    const ushort* __restrict__ Bh, const ushort* __restrict__ Bl,
    const float* __restrict__ bq, const float* __restrict__ bk_, const float* __restrict__ bv,
    float* __restrict__ q, float* __restrict__ k, float* __restrict__ v,
    float* __restrict__ attns)
{
    const int tid = threadIdx.x;

    if (blockIdx.x >= 384) {
        const float c = 1.0f / (float)LL;
        const float4 val = make_float4(c, c, c, c);
        float4* p = (float4*)attns + (long)(blockIdx.x - 384) * 8192 + tid;
        #pragma unroll
        for (int i = 0; i < 32; ++i) p[i * 256] = val;
        return;
    }

    const int pz = blockIdx.x >> 7;
    const int rem = blockIdx.x & 127;
    const int o0 = (rem >> 5) * 128;
    const int m0 = (rem & 31) * 128;
    const float* bias = (pz == 0) ? bq : ((pz == 1) ? bk_ : bv);
    float* out = (pz == 0) ? q : ((pz == 1) ? k : v);

    const ushort* Bp = Bh + (long)pz * DD * DD;
    const ushort* Blp = Bl + (long)pz * DD * DD;
    const ushort* segA[3] = {Ah, Ah, Al};
    const ushort* segB[3] = {Bp, Blp, Bp};

    __shared__ __attribute__((aligned(16))) ushort As[128 * 64];
    __shared__ __attribute__((aligned(16))) ushort Bs[128 * 64];

    const int lane = tid & 63, w = tid >> 6;
    const int wr = w >> 1, wc = w & 1;
    const int ln15 = lane & 15;
    const int l3 = lane >> 3, l7 = (lane & 7) * 8;

    f32x4 acc[4][4] = {};

    // v (pz==2): single bf16 term xh*Wvh (8 steps); q,k: full 3-term split (24 steps)
    const int tmax = (pz == 2) ? 8 : 24;
    for (int t = 0; t < tmax; ++t) {
        const ushort* Aseg = segA[t >> 3];
        const ushort* Bseg = segB[t >> 3];
        const int k0 = (t & 7) * 64;
        __syncthreads();
        #pragma unroll
        for (int c = 0; c < 8; ++c) {
            const int j = w * 8 + c;
            if (j < 16) {
                gload16(Aseg + (long)(m0 + j * 8 + l3) * DD + k0 + l7,
                        (char*)As + j * 1024);
            } else {
                const int j2 = j - 16;
                gload16(Bseg + (long)(o0 + j2 * 8 + l3) * DD + k0 + l7,
                        (char*)Bs + j2 * 1024);
            }
        }
        __syncthreads();
        #pragma unroll
        for (int ks = 0; ks < 2; ++ks) {
            const int kb = ks * 64 + (lane >> 4) * 16;
            bf16x8 bfr[4];
            #pragma unroll
            for (int jj = 0; jj < 4; ++jj)
                bfr[jj] = *(const bf16x8*)((const char*)Bs + (wc * 64 + jj * 16 + ln15) * 128 + kb);
            #pragma unroll
            for (int i = 0; i < 4; ++i) {
                bf16x8 af = *(const bf16x8*)((const char*)As + (wr * 64 + i * 16 + ln15) * 128 + kb);
                #pragma unroll
                for (int jj = 0; jj < 4; ++jj)
                    acc[i][jj] = __builtin_amdgcn_mfma_f32_16x16x32_bf16(af, bfr[jj], acc[i][jj], 0, 0, 0);
            }
        }
    }

    const int n_base = o0 + wc * 64;
    float bb[4];
    #pragma unroll
    for (int jj = 0; jj < 4; ++jj) bb[jj] = bias[n_base + jj * 16 + ln15];
    #pragma unroll
    for (int i = 0; i < 4; ++i) {
        #pragma unroll
        for (int jj = 0; jj < 4; ++jj) {
            const int n = n_base + jj * 16 + ln15;
            #pragma unroll
            for (int r = 0; r < 4; ++r) {
                const int m = m0 + wr * 64 + i * 16 + (lane >> 4) * 4 + r;
                out[(((long)(m >> 11) * HH + (n >> 6)) * LL + (m & (LL - 1))) * DK + (n & 63)] =
                    acc[i][jj][r] + bb[jj];
            }
        }
    }
}

// =============== K2: qk 4-way XCD-swizzled (0..511) || cumsum_p1 (512..767) — R12 verbatim ===============
__global__ __launch_bounds__(256) void k2_qk_cumsum1(
    const float* __restrict__ q, const float* __restrict__ k, const float* __restrict__ v,
    const int* __restrict__ idxs, float* __restrict__ M, float* __restrict__ sums)
{
    const int tid = threadIdx.x;

    if (blockIdx.x >= 512) {
        const int b = blockIdx.x - 512;          // 0..255, 16 per bh
        const int r8 = b & 7, t = b >> 3;        // t: 0..31
        const int bh = ((t >> 4) << 3) | r8;     // bh % 8 == bid % 8
        const int cgrp = t & 15;
        const int d = tid & 63, sc_ = tid >> 6;
        const int chunk = cgrp * 4 + sc_;
        const float* vb = v + ((long)bh * LL + chunk * 32) * DK + d;
        float s = 0.f;
        #pragma unroll
        for (int r = 0; r < 32; ++r) s += vb[r * DK];
        sums[((long)bh * 64 + chunk) * DK + d] = s;
        return;
    }

    // qk: 32 blocks per bh, swizzled so all land on XCD (bh & 7)
    const int r8 = blockIdx.x & 7, t = blockIdx.x >> 3;   // t: 0..63
    const int bh = ((t >> 5) << 3) | r8;
    const int j = t & 31;                                 // query chunk within bh
    const int l = j * 64 + (tid >> 2);
    const int part = tid & 3;
    const float* qr = q + ((long)bh * LL + l) * DK;
    float4 qv[16];
    #pragma unroll
    for (int i = 0; i < 16; ++i) qv[i] = *(const float4*)&qr[i * 4];

    const int* ir = idxs + (long)l * SK + part * 10;
    const float* kb = k + (long)bh * LL * DK;
    float mx = -INFINITY, sm = 0.f;
    #pragma unroll
    for (int s = 0; s < 10; ++s) {
        const float* kr = kb + (long)ir[s] * DK;
        float acc = 0.f;
        #pragma unroll
        for (int i = 0; i < 16; ++i) {
            float4 kv = *(const float4*)&kr[i * 4];
            acc += qv[i].x * kv.x + qv[i].y * kv.y + qv[i].z * kv.z + qv[i].w * kv.w;
        }
        mx = fmaxf(mx, acc); sm += acc;
    }
    mx = fmaxf(mx, __shfl_xor(mx, 1, 64));
    mx = fmaxf(mx, __shfl_xor(mx, 2, 64));
    sm += __shfl_xor(sm, 1, 64);
    sm += __shfl_xor(sm, 2, 64);
    if (part == 0) M[(long)bh * LL + l] = mx - sm * (1.0f / (float)LL);
}

// =============== K4: topk-recompute + {scores 5 rows (0..127) | cum-emit (128..383)}, XCD-swizzled — R12 verbatim ===============
__global__ __launch_bounds__(256) void k4_all(
    const float* __restrict__ q, const float* __restrict__ k, const float* __restrict__ v,
    const float* __restrict__ M, const float* __restrict__ sums,
    float* __restrict__ attns, float* __restrict__ ctx)
{
    const int tid = threadIdx.x;
    const bool isCum = blockIdx.x >= 128;
    int bh, role;
    if (isCum) {
        const int b = blockIdx.x - 128;
        const int r8 = b & 7, t = b >> 3;
        bh = ((t >> 4) << 3) | r8;
        role = t & 15;
    } else {
        const int r8 = blockIdx.x & 7, t = blockIdx.x >> 3;
        bh = ((t >> 3) << 3) | r8;
        role = t & 7;
    }

    __shared__ int list[UU];
    __shared__ unsigned bmap[64];

    if (tid < 64) bmap[tid] = 0u;
    __syncthreads();
    if (tid < 64) {
        const int lane = tid;
        float vals[32];
        #pragma unroll
        for (int r = 0; r < 32; ++r) vals[r] = M[(long)bh * LL + r * 64 + lane];
        for (int it = 0; it < UU; ++it) {
            float lm = vals[0];
            #pragma unroll
            for (int r = 1; r < 32; ++r) lm = fmaxf(lm, vals[r]);
            float wm = lm;
            #pragma unroll
            for (int s = 1; s < 64; s <<= 1) wm = fmaxf(wm, __shfl_xor(wm, s, 64));
            unsigned long long mask = __ballot(lm == wm);
            int first = (int)__ffsll(mask) - 1;
            if (lane == first) {
                #pragma unroll
                for (int r = 0; r < 32; ++r) {
                    if (vals[r] == wm) { list[it] = r * 64 + lane; vals[r] = -INFINITY; break; }
                }
            }
        }
    }
    __syncthreads();
    if (tid < UU) atomicOr(&bmap[list[tid] >> 5], 1u << (list[tid] & 31));
    __syncthreads();

    if (isCum) {
        const int d = tid & 63, sc_ = tid >> 6;
        const int chunk = role * 4 + sc_;
        float carry = 0.f;
        for (int c = 0; c < chunk; ++c) carry += sums[((long)bh * 64 + c) * DK + d];
        const float* vb = v + ((long)bh * LL + chunk * 32) * DK + d;
        float* cb = ctx + ((long)bh * LL + chunk * 32) * DK + d;
        float run = carry;
        #pragma unroll
        for (int r = 0; r < 32; ++r) {
            run += vb[r * DK];
            const int l = chunk * 32 + r;
            if (!((bmap[l >> 5] >> (l & 31)) & 1u)) cb[r * DK] = run;
        }
        return;
    }

    const int g = role;
    const int lane = tid & 63, wave = tid >> 6;
    __shared__ float qs[5][DK];
    __shared__ float sc[5][LL];          // 40 KB
    __shared__ float red[5][4];
    __shared__ float red2[4][5][DK];     // 5 KB

    if (tid < 80) {
        int u = tid >> 4, c4 = (tid & 15) * 4;
        *(float4*)&qs[u][c4] = *(const float4*)&q[((long)bh * LL + list[g * 5 + u]) * DK + c4];
    }
    __syncthreads();

    const float* kb = k + (long)bh * LL * DK;
    float a[8][5] = {};
    #pragma unroll
    for (int c = 0; c < DK; c += 4) {
        float4 qv[5];
        #pragma unroll
        for (int u = 0; u < 5; ++u) qv[u] = *(const float4*)&qs[u][c];
        #pragma unroll
        for (int r = 0; r < 8; ++r) {
            float4 kv = *(const float4*)&kb[(long)(tid + r * 256) * DK + c];
            #pragma unroll
            for (int u = 0; u < 5; ++u)
                a[r][u] += qv[u].x * kv.x + qv[u].y * kv.y + qv[u].z * kv.z + qv[u].w * kv.w;
        }
    }
    const float scale = 0.125f;
    #pragma unroll
    for (int r = 0; r < 8; ++r)
        #pragma unroll
        for (int u = 0; u < 5; ++u)
            sc[u][tid + r * 256] = a[r][u] * scale;
    __syncthreads();

    float xv[5][8];
    #pragma unroll
    for (int u = 0; u < 5; ++u) {
        float4 t0 = *(const float4*)&sc[u][tid * 8];
        float4 t1 = *(const float4*)&sc[u][tid * 8 + 4];
        xv[u][0] = t0.x; xv[u][1] = t0.y; xv[u][2] = t0.z; xv[u][3] = t0.w;
        xv[u][4] = t1.x; xv[u][5] = t1.y; xv[u][6] = t1.z; xv[u][7] = t1.w;
    }
    float mloc[5];
    #pragma unroll
    for (int u = 0; u < 5; ++u) {
        float m = xv[u][0];
        #pragma unroll
        for (int i = 1; i < 8; ++i) m = fmaxf(m, xv[u][i]);
        #pragma unroll
        for (int s = 1; s < 64; s <<= 1) m = fmaxf(m, __shfl_xor(m, s, 64));
        if (lane == 0) red[u][wave] = m;
        mloc[u] = m;
    }
    __syncthreads();
    #pragma unroll
    for (int u = 0; u < 5; ++u)
        mloc[u] = fmaxf(fmaxf(red[u][0], red[u][1]), fmaxf(red[u][2], red[u][3]));
    __syncthreads();
    #pragma unroll
    for (int u = 0; u < 5; ++u) {
        float s = 0.f;
        #pragma unroll
        for (int i = 0; i < 8; ++i) { xv[u][i] = expf(xv[u][i] - mloc[u]); s += xv[u][i]; }
        #pragma unroll
        for (int st = 1; st < 64; st <<= 1) s += __shfl_xor(s, st, 64);
        if (lane == 0) red[u][wave] = s;
    }
    __syncthreads();
    #pragma unroll
    for (int u = 0; u < 5; ++u) {
        float inv = 1.0f / (red[u][0] + red[u][1] + red[u][2] + red[u][3]);
        float* row = attns + ((long)bh * LL + list[g * 5 + u]) * LL;
        float4 o0, o1;
        o0.x = xv[u][0] * inv; o0.y = xv[u][1] * inv; o0.z = xv[u][2] * inv; o0.w = xv[u][3] * inv;
        o1.x = xv[u][4] * inv; o1.y = xv[u][5] * inv; o1.z = xv[u][6] * inv; o1.w = xv[u][7] * inv;
        *(float4*)&row[tid * 8] = o0;
        *(float4*)&row[tid * 8 + 4] = o1;
        *(float4*)&sc[u][tid * 8] = o0;
        *(float4*)&sc[u][tid * 8 + 4] = o1;
    }
    __syncthreads();

    const int d = tid & 63, part = tid >> 6;
    const float* vb = v + (long)bh * LL * DK + d;
    float ua[5] = {};
    for (int l0 = part * 512; l0 < part * 512 + 512; l0 += 4) {
        float vv0 = vb[(long)(l0 + 0) * DK];
        float vv1 = vb[(long)(l0 + 1) * DK];
        float vv2 = vb[(long)(l0 + 2) * DK];
        float vv3 = vb[(long)(l0 + 3) * DK];
        #pragma unroll
        for (int u = 0; u < 5; ++u) {
            float4 pv = *(const float4*)&sc[u][l0];
            ua[u] += pv.x * vv0 + pv.y * vv1 + pv.z * vv2 + pv.w * vv3;
        }
    }
    #pragma unroll
    for (int u = 0; u < 5; ++u) red2[part][u][d] = ua[u];
    __syncthreads();
    if (part == 0) {
        #pragma unroll
        for (int u = 0; u < 5; ++u) {
            float s = red2[0][u][d] + red2[1][u][d] + red2[2][u][d] + red2[3][u][d];
            ctx[((long)bh * LL + list[g * 5 + u]) * DK + d] = s;
        }
    }
}

extern "C" void kernel_launch(void* const* d_in, const int* in_sizes, int n_in,
                              void* d_out, int out_size, void* d_ws, size_t ws_size,
                              hipStream_t stream) {
    const float* x  = (const float*)d_in[0];
    const float* Wq = (const float*)d_in[1];
    const float* bq = (const float*)d_in[2];
    const float* Wk = (const float*)d_in[3];
    const float* bk = (const float*)d_in[4];
    const float* Wv = (const float*)d_in[5];
    const float* bv = (const float*)d_in[6];
    const int* idxs = (const int*)d_in[7];

    float* ctx   = (float*)d_out;                            // B*H*L*DK (8 MB)
    float* attns = (float*)d_out + (long)BB * HH * LL * DK;  // B*H*L*L (268 MB)

    char* w = (char*)d_ws;
    float* q    = (float*)w; w += (size_t)BB * HH * LL * DK * 4;
    float* k    = (float*)w; w += (size_t)BB * HH * LL * DK * 4;
    float* v    = (float*)w; w += (size_t)BB * HH * LL * DK * 4;
    float* M    = (float*)w; w += (size_t)BB * HH * LL * 4;
    float* sums = (float*)w; w += (size_t)BH * 64 * DK * 4;
    ushort* Bh  = (ushort*)w; w += (size_t)3 * DD * DD * 2;
    ushort* Bl  = (ushort*)w; w += (size_t)3 * DD * DD * 2;

    // Ah/Al live in the ctx output region (consumed by K1; ctx written in K4)
    ushort* Ah = (ushort*)ctx;                  // 4 MB
    ushort* Al = Ah + (size_t)4096 * DD;        // 4 MB

    // K0: split-bf16 packing
    pack_split<<<1408, 256, 0, stream>>>(x, Wq, Wk, Wv, Ah, Al, Bh, Bl);

    // K1: MFMA projections, v 1-term (384) || fill attns ALL units (2048)
    k1_proj_fill<<<384 + 2048, 256, 0, stream>>>(Ah, Al, Bh, Bl, bq, bk, bv, q, k, v, attns);

    // K2: sampled QK^T 4-way XCD-swizzled (512) || cumsum sums (256)
    k2_qk_cumsum1<<<512 + 256, 256, 0, stream>>>(q, k, v, idxs, M, sums);

    // K4: topk-recompute + scores/softmax/upd/scatter (128) || cumsum emit (256), XCD-swizzled
    k4_all<<<128 + 256, 256, 0, stream>>>(q, k, v, M, sums, attns, ctx);
}